// Round 1
// baseline (1451.726 us; speedup 1.0000x reference)
//
#include <hip/hip_runtime.h>

typedef unsigned short u16;
typedef unsigned int u32;
typedef __attribute__((ext_vector_type(8))) short bf16x8;   // 8 bf16 = 4 VGPRs
typedef __attribute__((ext_vector_type(4))) float f32x4;
typedef __attribute__((ext_vector_type(4))) u16 u16x4;
typedef __attribute__((ext_vector_type(8))) u16 u16x8;

#define N_NODES 20000
#define N_EDGES 320000
#define F_IN 128
#define HID 256
#define OUT_F 32
#define N_LAYERS 30
#define N_GRAPHS 16
#define ELLCAP 64

// ---------------- bf16 split helpers ----------------
__device__ __forceinline__ u16 f32_to_bf16(float f) {
    u32 u = __float_as_uint(f);
    u32 r = (u + 0x7FFFu + ((u >> 16) & 1u)) >> 16;   // round-to-nearest-even
    return (u16)r;
}
__device__ __forceinline__ float bf16_to_f32(u16 h) {
    return __uint_as_float(((u32)h) << 16);
}

__device__ __forceinline__ void gl_lds16(const u16* g, u16* l) {
    __builtin_amdgcn_global_load_lds((const u32*)g, (u32*)l, 16, 0, 0);
}

// ---------------- graph build ----------------
// fill_ell also produces the degree: cursor's final value == in-degree at dst.
// ell_col is pre-zeroed; unfilled slots stay 0 (node 0: valid, masked off in agg).
__global__ void fill_ell_kernel(const int* __restrict__ src, const int* __restrict__ dst,
                                int* __restrict__ cursor, u16* __restrict__ ell_col, int E) {
    int e = blockIdx.x * blockDim.x + threadIdx.x;
    if (e >= E) return;
    int s = src[e], d = dst[e];
    int slot = atomicAdd(&cursor[d], 1);
    if (slot < ELLCAP) ell_col[d * ELLCAP + slot] = (u16)s;
}

__global__ void dinv_kernel(const int* __restrict__ cnt, float* __restrict__ dinv, int n) {
    int i = blockIdx.x * blockDim.x + threadIdx.x;
    if (i < n) dinv[i] = rsqrtf((float)(cnt[i] + 1));  // +1 self loop
}

// x' = dinv ⊙ x, dinv computed inline from degree (no dependency on dinv_kernel)
__global__ void prescale_x_kernel(const float* __restrict__ x, const int* __restrict__ cnt,
                                  float* __restrict__ xs, int total) {
    int i = blockIdx.x * 256 + threadIdx.x;
    if (i < total) xs[i] = x[i] * rsqrtf((float)(cnt[i >> 7] + 1));   // F_IN = 128
}

// ---------------- weight split+transpose (LDS-tiled, coalesced writes) ----------------
// W [L][K][N] -> Th/Tl [L][N][K]; 32x32 tiles.
__global__ __launch_bounds__(256) void transpose_split_tiled(const float* __restrict__ W,
                                                             u16* __restrict__ Th, u16* __restrict__ Tl,
                                                             int K, int N) {
    __shared__ float tile[32][33];
    const int l = blockIdx.y;
    const int ntn = N >> 5;
    const int kt = blockIdx.x / ntn, ntile = blockIdx.x % ntn;
    const float* Wl = W + (size_t)l * K * N;
    u16* Thl = Th + (size_t)l * K * N;
    u16* Tll = Tl + (size_t)l * K * N;
    const int r8 = threadIdx.x >> 5, c = threadIdx.x & 31;
    #pragma unroll
    for (int rr = 0; rr < 4; ++rr) {
        int r = rr * 8 + r8;
        tile[r][c] = Wl[(size_t)(kt * 32 + r) * N + ntile * 32 + c];
    }
    __syncthreads();
    #pragma unroll
    for (int rr = 0; rr < 4; ++rr) {
        int n = rr * 8 + r8;                 // transposed row (N dim)
        float v = tile[c][n];                // W[k=kt*32+c][n]
        u16 hb = f32_to_bf16(v);
        u16 lb = f32_to_bf16(v - bf16_to_f32(hb));
        size_t o = (size_t)(ntile * 32 + n) * K + kt * 32 + c;
        Thl[o] = hb;
        Tll[o] = lb;
    }
}

// ---------------- feature-split aggregation ----------------
// g[d] = dinv[d] * (sum_{s in N(d)} hs[s] + hs[d]), hs pre-scaled by dinv.
// Block = 32 nodes x one 32-feature chunk; fc = blockIdx & (CHUNKS-1): round-robin
// block->XCD dispatch pins one feature slice (2.56 MB) per XCD L2.
// 8 lanes/node, f32x4/lane. Full 8-batches only (zero-padded ELL, masked final adds)
// -> one waitcnt per batch, no serial-latency tail. Depth-2 software pipeline.
// NOTE (R12 analysis): this kernel runs at the per-XCD L2 request-rate roofline
// (~340K line-touches/XCD/layer); byte-level re-chunking cannot reduce it.
template <int F>
__global__ __launch_bounds__(256) void agg_fsplit(const float* __restrict__ hs,
                                                  const u16* __restrict__ ell_col,
                                                  const int* __restrict__ cnt,
                                                  const float* __restrict__ dinv,
                                                  u16* __restrict__ ghi, u16* __restrict__ glo) {
    constexpr int CHUNKS = F / 32;
    __shared__ u16 cols[32 * ELLCAP];
    const int blk = blockIdx.x;
    const int fc = blk & (CHUNKS - 1);
    const int grp = blk / CHUNKS;
    const int node0 = grp * 32;
    const int tid = threadIdx.x;
    *(u16x8*)&cols[tid * 8] = *(const u16x8*)&ell_col[(size_t)node0 * ELLCAP + tid * 8];
    const int g = tid >> 3, sub = tid & 7;
    const int node = node0 + g;
    const int f = fc * 32 + sub * 4;
    int c = cnt[node]; c = c < ELLCAP ? c : ELLCAP;
    const float dd = dinv[node];
    f32x4 acc = *(const f32x4*)(hs + (size_t)node * F + f);   // self loop (pre-scaled)
    __syncthreads();
    const u16* cl = &cols[g * ELLCAP];
    const int nb = (c + 7) >> 3;   // number of 8-batches (last one masked)
    if (nb > 0) {
        const f32x4 zero = {0.f, 0.f, 0.f, 0.f};
        f32x4 vbuf[8];
        u16x8 cc = *(const u16x8*)&cl[0];
        #pragma unroll
        for (int j = 0; j < 8; ++j) vbuf[j] = *(const f32x4*)(hs + (size_t)cc[j] * F + f);
        int base = 0;
        for (int b = 1; b < nb; ++b) {
            u16x8 cn = *(const u16x8*)&cl[b * 8];
            f32x4 vn[8];
            #pragma unroll
            for (int j = 0; j < 8; ++j) vn[j] = *(const f32x4*)(hs + (size_t)cn[j] * F + f);
            #pragma unroll
            for (int j = 0; j < 8; ++j) acc += vbuf[j];   // non-final batches are full
            base += 8;
            #pragma unroll
            for (int j = 0; j < 8; ++j) vbuf[j] = vn[j];
        }
        #pragma unroll
        for (int j = 0; j < 8; ++j) acc += (base + j < c) ? vbuf[j] : zero;  // masked final batch
    }
    u16x4 vh, vl;
    #pragma unroll
    for (int i = 0; i < 4; ++i) {
        float v = acc[i] * dd;
        u16 hb = f32_to_bf16(v);
        vh[i] = hb;
        vl[i] = f32_to_bf16(v - bf16_to_f32(hb));
    }
    *(u16x4*)(ghi + (size_t)node * F + f) = vh;
    *(u16x4*)(glo + (size_t)node * F + f) = vl;
}

// ---------------- split-bf16 MFMA GEMM + bias + relu (+ optional row scale) ----------------
// C[M][N] = rowscale[m] * relu((Ah+Al)[M][K] @ (Bh+Bl)^T + bias), B transposed [N][K].
// Tile: 128(M) x 64(N) x 64(K), 3 blocks/CU — the best-measured configuration (R9).
// XCD-swizzled 1D grid: id = 8*(rowhi*NCOLT + ncol) + slot, row_tile = rowhi*8 + slot.
// All NCOLT n-tiles of a row share id%8 -> same XCD -> A row-tile re-read from L2.
#define NCOLT 4   // N/64 = 256/64
__global__ __launch_bounds__(256, 3) void gemm_bias_relu(const u16* __restrict__ Ah, const u16* __restrict__ Al,
                                                         const u16* __restrict__ Bh, const u16* __restrict__ Bl,
                                                         const float* __restrict__ bias,
                                                         const float* __restrict__ rowscale,
                                                         float* __restrict__ C, int M, int K, int N) {
    __shared__ __align__(16) u16 As_h[128 * 64];
    __shared__ __align__(16) u16 As_l[128 * 64];
    __shared__ __align__(16) u16 Bs_h[64 * 64];
    __shared__ __align__(16) u16 Bs_l[64 * 64];
    const int bid = blockIdx.x;
    const int slot = bid & 7;
    const int j = bid >> 3;
    const int ncol = j & (NCOLT - 1);
    const int rowhi = j / NCOLT;
    const int row_tile = rowhi * 8 + slot;
    const int row0 = row_tile * 128;
    if (row0 >= M) return;
    const int n0 = ncol * 64;
    const int tid = threadIdx.x;
    const int wave = tid >> 6, lane = tid & 63;
    const int wm = wave >> 1, wn = wave & 1;
    const int lr = lane >> 3;   // row within 8-row staging group
    const int lc = lane & 7;    // 16B-chunk position within row
    f32x4 acc[4][2] = {};

    for (int k0 = 0; k0 < K; k0 += 64) {
        // stage A hi/lo: 128 rows x 64 k, XOR-swizzled chunks
        #pragma unroll
        for (int q = 0; q < 4; ++q) {
            int rl = (wave * 4 + q) * 8 + lr;
            int ra = row0 + rl; ra = ra < M ? ra : (M - 1);   // clamp tail (rows >= M unused)
            int cg = (lc ^ (rl & 7)) << 3;
            gl_lds16(Ah + (size_t)ra * K + k0 + cg, &As_h[(wave * 4 + q) * 512]);
            gl_lds16(Al + (size_t)ra * K + k0 + cg, &As_l[(wave * 4 + q) * 512]);
        }
        // stage B^T hi/lo: 64 n-rows x 64 k
        #pragma unroll
        for (int q = 0; q < 2; ++q) {
            int rl = (wave * 2 + q) * 8 + lr;
            int ng = n0 + rl;
            int cg = (lc ^ (rl & 7)) << 3;
            gl_lds16(Bh + (size_t)ng * K + k0 + cg, &Bs_h[(wave * 2 + q) * 512]);
            gl_lds16(Bl + (size_t)ng * K + k0 + cg, &Bs_l[(wave * 2 + q) * 512]);
        }
        __syncthreads();
        #pragma unroll
        for (int kk = 0; kk < 2; ++kk) {
            const int cidx = kk * 4 + (lane >> 4);
            bf16x8 bhf[2], blf[2];
            #pragma unroll
            for (int nt = 0; nt < 2; ++nt) {
                int nl = wn * 32 + nt * 16 + (lane & 15);
                int off = nl * 64 + ((cidx ^ (nl & 7)) << 3);
                bhf[nt] = *(const bf16x8*)&Bs_h[off];
                blf[nt] = *(const bf16x8*)&Bs_l[off];
            }
            #pragma unroll
            for (int mt = 0; mt < 4; ++mt) {
                int ml = wm * 64 + mt * 16 + (lane & 15);
                int off = ml * 64 + ((cidx ^ (ml & 7)) << 3);
                bf16x8 ah = *(const bf16x8*)&As_h[off];
                bf16x8 al = *(const bf16x8*)&As_l[off];
                #pragma unroll
                for (int nt = 0; nt < 2; ++nt) {
                    acc[mt][nt] = __builtin_amdgcn_mfma_f32_16x16x32_bf16(ah, bhf[nt], acc[mt][nt], 0, 0, 0);
                    acc[mt][nt] = __builtin_amdgcn_mfma_f32_16x16x32_bf16(ah, blf[nt], acc[mt][nt], 0, 0, 0);
                    acc[mt][nt] = __builtin_amdgcn_mfma_f32_16x16x32_bf16(al, bhf[nt], acc[mt][nt], 0, 0, 0);
                }
            }
        }
        __syncthreads();
    }
    // epilogue: bias + relu (+ dinv row scale); C/D layout col=lane&15, row=(lane>>4)*4+r
    #pragma unroll
    for (int mt = 0; mt < 4; ++mt) {
        int gr = row0 + wm * 64 + mt * 16 + ((lane >> 4) << 2);
        #pragma unroll
        for (int r = 0; r < 4; ++r) {
            if (gr + r >= M) continue;
            float sc = rowscale ? rowscale[gr + r] : 1.f;
            #pragma unroll
            for (int nt = 0; nt < 2; ++nt) {
                int gc = n0 + wn * 32 + nt * 16 + (lane & 15);
                C[(size_t)(gr + r) * N + gc] = sc * fmaxf(acc[mt][nt][r] + bias[gc], 0.f);
            }
        }
    }
}

// ---------------- pooling ----------------
#define POOL_CHUNK 32
__global__ __launch_bounds__(256) void pool_kernel(const float* __restrict__ h,
                                                   const int* __restrict__ batch,
                                                   float* __restrict__ pool_sum) {
    int f = threadIdx.x;
    int start = blockIdx.x * POOL_CHUNK;
    int end = start + POOL_CHUNK; end = end < N_NODES ? end : N_NODES;
    if (start >= N_NODES) return;
    int gcur = batch[start];
    float acc = 0.f;
    for (int i = start; i < end; ++i) {
        int g = batch[i];
        if (g != gcur) { atomicAdd(&pool_sum[gcur * HID + f], acc); acc = 0.f; gcur = g; }
        acc += h[(size_t)i * HID + f];
    }
    atomicAdd(&pool_sum[gcur * HID + f], acc);
}

__device__ int lb_int(const int* __restrict__ a, int n, int v) {
    int lo = 0, hi = n;
    while (lo < hi) {
        int mid = (lo + hi) >> 1;
        if (a[mid] < v) lo = mid + 1; else hi = mid;
    }
    return lo;
}

__global__ void final_linear_kernel(const float* __restrict__ pool_sum,
                                    const int* __restrict__ batch,
                                    const float* __restrict__ Wlin,
                                    const float* __restrict__ blin,
                                    float* __restrict__ out) {
    int idx = blockIdx.x * blockDim.x + threadIdx.x;
    if (idx >= N_GRAPHS * OUT_F) return;
    int g = idx / OUT_F, o = idx % OUT_F;
    int lo = lb_int(batch, N_NODES, g);
    int hi = lb_int(batch, N_NODES, g + 1);
    float cinv = 1.f / fmaxf((float)(hi - lo), 1.f);
    float s = blin[o];
    for (int k = 0; k < HID; ++k) s += (pool_sum[g * HID + k] * cinv) * Wlin[k * OUT_F + o];
    out[idx] = s;
}

// ---------------- launch ----------------
static inline size_t align_up(size_t x, size_t a) { return (x + a - 1) & ~(a - 1); }

extern "C" void kernel_launch(void* const* d_in, const int* in_sizes, int n_in,
                              void* d_out, int out_size, void* d_ws, size_t ws_size,
                              hipStream_t stream) {
    const float* x     = (const float*)d_in[0];
    const int*   elist = (const int*)d_in[1];   // [2, E]
    const int*   batch = (const int*)d_in[2];
    const float* W1    = (const float*)d_in[3];
    const float* b1    = (const float*)d_in[4];
    const float* Wm    = (const float*)d_in[5];
    const float* bm    = (const float*)d_in[6];
    const float* Wlin  = (const float*)d_in[7];
    const float* blin  = (const float*)d_in[8];
    float* outp = (float*)d_out;

    const int* srcA = elist;
    const int* dstA = elist + N_EDGES;

    char* ws = (char*)d_ws;
    size_t off = 0;
    float* h      = (float*)(ws + off); off = align_up(off + sizeof(float) * N_NODES * HID, 1024);
    float* xs     = (float*)(ws + off); off = align_up(off + sizeof(float) * N_NODES * F_IN, 1024);
    u16*   g_hi   = (u16*)(ws + off);   off = align_up(off + sizeof(u16) * N_NODES * HID, 1024);
    u16*   g_lo   = (u16*)(ws + off);   off = align_up(off + sizeof(u16) * N_NODES * HID, 1024);
    u16*   W1T_h  = (u16*)(ws + off);   off = align_up(off + sizeof(u16) * F_IN * HID, 1024);
    u16*   W1T_l  = (u16*)(ws + off);   off = align_up(off + sizeof(u16) * F_IN * HID, 1024);
    u16*   WmT_h  = (u16*)(ws + off);   off = align_up(off + sizeof(u16) * (N_LAYERS - 1) * HID * HID, 1024);
    u16*   WmT_l  = (u16*)(ws + off);   off = align_up(off + sizeof(u16) * (N_LAYERS - 1) * HID * HID, 1024);
    int*   cursor = (int*)(ws + off);   off = align_up(off + sizeof(int) * N_NODES, 1024);
    float* dinv   = (float*)(ws + off); off = align_up(off + sizeof(float) * N_NODES, 1024);
    u16*   ell_col = (u16*)(ws + off);  off = align_up(off + sizeof(u16) * N_NODES * ELLCAP, 1024);
    float* pool_sum = (float*)(ws + off); off = align_up(off + sizeof(float) * N_GRAPHS * HID, 1024);

    hipMemsetAsync(cursor, 0, sizeof(int) * N_NODES, stream);
    hipMemsetAsync(ell_col, 0, sizeof(u16) * N_NODES * ELLCAP, stream);  // pad slots -> node 0 (masked)
    hipMemsetAsync(pool_sum, 0, sizeof(float) * N_GRAPHS * HID, stream);

    fill_ell_kernel<<<(N_EDGES + 255) / 256, 256, 0, stream>>>(srcA, dstA, cursor, ell_col, N_EDGES);
    dinv_kernel<<<(N_NODES + 255) / 256, 256, 0, stream>>>(cursor, dinv, N_NODES);
    prescale_x_kernel<<<(N_NODES * F_IN + 255) / 256, 256, 0, stream>>>(x, cursor, xs, N_NODES * F_IN);

    transpose_split_tiled<<<dim3((F_IN / 32) * (HID / 32), 1), 256, 0, stream>>>(W1, W1T_h, W1T_l, F_IN, HID);
    transpose_split_tiled<<<dim3((HID / 32) * (HID / 32), N_LAYERS - 1), 256, 0, stream>>>(Wm, WmT_h, WmT_l, HID, HID);

    const int n_row_tiles = (N_NODES + 127) / 128;            // 157
    const int ggrid = ((n_row_tiles + 7) / 8) * 8 * NCOLT;    // 640 (holes guarded in-kernel)
    // layer 1: g = agg(xs) [K=128]; h' = dinv * relu(g @ W1 + b1)
    agg_fsplit<F_IN><<<(N_NODES / 32) * (F_IN / 32), 256, 0, stream>>>(xs, ell_col, cursor, dinv, g_hi, g_lo);
    gemm_bias_relu<<<ggrid, 256, 0, stream>>>(g_hi, g_lo, W1T_h, W1T_l, b1, dinv, h, N_NODES, F_IN, HID);
    // middle layers: g = agg(h'); h' = dinv * relu(g @ W + b)  (last: unscaled for pooling)
    for (int l = 0; l < N_LAYERS - 1; ++l) {
        agg_fsplit<HID><<<(N_NODES / 32) * (HID / 32), 256, 0, stream>>>(h, ell_col, cursor, dinv, g_hi, g_lo);
        const float* rs = (l == N_LAYERS - 2) ? nullptr : dinv;
        gemm_bias_relu<<<ggrid, 256, 0, stream>>>(g_hi, g_lo, WmT_h + (size_t)l * HID * HID,
                                                  WmT_l + (size_t)l * HID * HID,
                                                  bm + (size_t)l * HID, rs, h, N_NODES, HID, HID);
    }
    pool_kernel<<<(N_NODES + POOL_CHUNK - 1) / POOL_CHUNK, 256, 0, stream>>>(h, batch, pool_sum);
    final_linear_kernel<<<2, 256, 0, stream>>>(pool_sum, batch, Wlin, blin, outp);
}

// Round 2
// 1188.385 us; speedup vs baseline: 1.2216x; 1.2216x over previous
//
#include <hip/hip_runtime.h>

typedef unsigned short u16;
typedef unsigned int u32;
typedef __attribute__((ext_vector_type(8))) short bf16x8;   // 8 bf16 = 4 VGPRs
typedef __attribute__((ext_vector_type(4))) float f32x4;
typedef __attribute__((ext_vector_type(4))) u16 u16x4;
typedef __attribute__((ext_vector_type(8))) u16 u16x8;

#define N_NODES 20000
#define N_EDGES 320000
#define F_IN 128
#define HID 256
#define OUT_F 32
#define N_LAYERS 30
#define N_GRAPHS 16
#define ELLCAP 64

// ---------------- bf16 / fp16 helpers ----------------
__device__ __forceinline__ u16 f32_to_bf16(float f) {
    u32 u = __float_as_uint(f);
    u32 r = (u + 0x7FFFu + ((u >> 16) & 1u)) >> 16;   // round-to-nearest-even
    return (u16)r;
}
__device__ __forceinline__ float bf16_to_f32(u16 h) {
    return __uint_as_float(((u32)h) << 16);
}
__device__ __forceinline__ float h2f(u16 u) {
    _Float16 h;
    __builtin_memcpy(&h, &u, 2);
    return (float)h;
}
__device__ __forceinline__ u16 f2h(float f) {
    _Float16 h = (_Float16)f;
    u16 u;
    __builtin_memcpy(&u, &h, 2);
    return u;
}

__device__ __forceinline__ void gl_lds16(const u16* g, u16* l) {
    __builtin_amdgcn_global_load_lds((const u32*)g, (u32*)l, 16, 0, 0);
}

// ---------------- graph build ----------------
// fill_ell also produces the degree: cursor's final value == in-degree at dst.
// ell_col is pre-zeroed; unfilled slots stay 0 (node 0: valid, masked off in agg).
__global__ void fill_ell_kernel(const int* __restrict__ src, const int* __restrict__ dst,
                                int* __restrict__ cursor, u16* __restrict__ ell_col, int E) {
    int e = blockIdx.x * blockDim.x + threadIdx.x;
    if (e >= E) return;
    int s = src[e], d = dst[e];
    int slot = atomicAdd(&cursor[d], 1);
    if (slot < ELLCAP) ell_col[d * ELLCAP + slot] = (u16)s;
}

__global__ void dinv_kernel(const int* __restrict__ cnt, float* __restrict__ dinv, int n) {
    int i = blockIdx.x * blockDim.x + threadIdx.x;
    if (i < n) dinv[i] = rsqrtf((float)(cnt[i] + 1));  // +1 self loop
}

// x' = fp16(dinv ⊙ x): gather source for layer-1 agg is fp16 (halves L2 line-touches)
__global__ void prescale_x_kernel(const float* __restrict__ x, const int* __restrict__ cnt,
                                  u16* __restrict__ xs, int total) {
    int i = blockIdx.x * 256 + threadIdx.x;
    if (i < total) xs[i] = f2h(x[i] * rsqrtf((float)(cnt[i >> 7] + 1)));   // F_IN = 128
}

// ---------------- weight split+transpose (LDS-tiled, coalesced writes) ----------------
// W [L][K][N] -> Th/Tl [L][N][K]; 32x32 tiles.
__global__ __launch_bounds__(256) void transpose_split_tiled(const float* __restrict__ W,
                                                             u16* __restrict__ Th, u16* __restrict__ Tl,
                                                             int K, int N) {
    __shared__ float tile[32][33];
    const int l = blockIdx.y;
    const int ntn = N >> 5;
    const int kt = blockIdx.x / ntn, ntile = blockIdx.x % ntn;
    const float* Wl = W + (size_t)l * K * N;
    u16* Thl = Th + (size_t)l * K * N;
    u16* Tll = Tl + (size_t)l * K * N;
    const int r8 = threadIdx.x >> 5, c = threadIdx.x & 31;
    #pragma unroll
    for (int rr = 0; rr < 4; ++rr) {
        int r = rr * 8 + r8;
        tile[r][c] = Wl[(size_t)(kt * 32 + r) * N + ntile * 32 + c];
    }
    __syncthreads();
    #pragma unroll
    for (int rr = 0; rr < 4; ++rr) {
        int n = rr * 8 + r8;                 // transposed row (N dim)
        float v = tile[c][n];                // W[k=kt*32+c][n]
        u16 hb = f32_to_bf16(v);
        u16 lb = f32_to_bf16(v - bf16_to_f32(hb));
        size_t o = (size_t)(ntile * 32 + n) * K + kt * 32 + c;
        Thl[o] = hb;
        Tll[o] = lb;
    }
}

// ---------------- feature-split aggregation (fp16 gather source) ----------------
// g[d] = dinv[d] * (sum_{s in N(d)} hs[s] + hs[d]), hs pre-scaled by dinv, stored fp16.
// Block = 32 nodes x one 64-feature chunk (one full 128B line per edge per chunk ->
// HALF the line-touches of the f32 version; the R12 L2 request-rate roofline scales
// with bytes/feature). 8 lanes/node, u16x8 (8 fp16) per lane, f32 accumulate.
// fc = blockIdx & (CHUNKS-1): round-robin block->XCD pins one 2.56MB slice per XCD L2.
// Full 8-batches only (zero-padded ELL, masked final adds); depth-2 software pipeline.
template <int F>
__global__ __launch_bounds__(256) void agg_fsplit_h(const u16* __restrict__ hs,
                                                    const u16* __restrict__ ell_col,
                                                    const int* __restrict__ cnt,
                                                    const float* __restrict__ dinv,
                                                    u16* __restrict__ ghi, u16* __restrict__ glo) {
    constexpr int CHUNKS = F / 64;
    __shared__ u16 cols[32 * ELLCAP];
    const int blk = blockIdx.x;
    const int fc = blk & (CHUNKS - 1);
    const int grp = blk / CHUNKS;
    const int node0 = grp * 32;
    const int tid = threadIdx.x;
    *(u16x8*)&cols[tid * 8] = *(const u16x8*)&ell_col[(size_t)node0 * ELLCAP + tid * 8];
    const int g = tid >> 3, sub = tid & 7;
    const int node = node0 + g;
    const int f = fc * 64 + sub * 8;
    int c = cnt[node]; c = c < ELLCAP ? c : ELLCAP;
    const float dd = dinv[node];
    f32x4 acc0 = {}, acc1 = {};
    {   // self loop (pre-scaled)
        u16x8 sv = *(const u16x8*)(hs + (size_t)node * F + f);
        #pragma unroll
        for (int i = 0; i < 4; ++i) acc0[i] += h2f(sv[i]);
        #pragma unroll
        for (int i = 0; i < 4; ++i) acc1[i] += h2f(sv[i + 4]);
    }
    __syncthreads();
    const u16* cl = &cols[g * ELLCAP];
    const int nb = (c + 7) >> 3;   // number of 8-batches (last one masked)
    if (nb > 0) {
        u16x8 vbuf[8];
        u16x8 cc = *(const u16x8*)&cl[0];
        #pragma unroll
        for (int j = 0; j < 8; ++j) vbuf[j] = *(const u16x8*)(hs + (size_t)cc[j] * F + f);
        int base = 0;
        for (int b = 1; b < nb; ++b) {
            u16x8 cn = *(const u16x8*)&cl[b * 8];
            u16x8 vn[8];
            #pragma unroll
            for (int j = 0; j < 8; ++j) vn[j] = *(const u16x8*)(hs + (size_t)cn[j] * F + f);
            #pragma unroll
            for (int j = 0; j < 8; ++j) {
                #pragma unroll
                for (int i = 0; i < 4; ++i) acc0[i] += h2f(vbuf[j][i]);
                #pragma unroll
                for (int i = 0; i < 4; ++i) acc1[i] += h2f(vbuf[j][i + 4]);
            }
            base += 8;
            #pragma unroll
            for (int j = 0; j < 8; ++j) vbuf[j] = vn[j];
        }
        const u16x8 zz = {};
        #pragma unroll
        for (int j = 0; j < 8; ++j) {
            u16x8 v = (base + j < c) ? vbuf[j] : zz;   // masked final batch (fp16 0x0000 == 0.0)
            #pragma unroll
            for (int i = 0; i < 4; ++i) acc0[i] += h2f(v[i]);
            #pragma unroll
            for (int i = 0; i < 4; ++i) acc1[i] += h2f(v[i + 4]);
        }
    }
    u16x8 vh, vl;
    #pragma unroll
    for (int i = 0; i < 4; ++i) {
        float v = acc0[i] * dd;
        u16 hb = f32_to_bf16(v);
        vh[i] = hb;
        vl[i] = f32_to_bf16(v - bf16_to_f32(hb));
    }
    #pragma unroll
    for (int i = 0; i < 4; ++i) {
        float v = acc1[i] * dd;
        u16 hb = f32_to_bf16(v);
        vh[i + 4] = hb;
        vl[i + 4] = f32_to_bf16(v - bf16_to_f32(hb));
    }
    *(u16x8*)(ghi + (size_t)node * F + f) = vh;
    *(u16x8*)(glo + (size_t)node * F + f) = vl;
}

// ---------------- split-bf16 MFMA GEMM + bias + relu (+ optional row scale) ----------------
// C[M][N] = rowscale[m] * relu((Ah+Al)[M][K] @ (Bh+Bl)^T + bias), B transposed [N][K].
// Tile: 128(M) x 64(N) x 64(K), 3 blocks/CU — the best-measured configuration (R9).
// XCD-swizzled 1D grid: id = 8*(rowhi*NCOLT + ncol) + slot, row_tile = rowhi*8 + slot.
// All NCOLT n-tiles of a row share id%8 -> same XCD -> A row-tile re-read from L2.
// Output: fp16 (Ch != nullptr, feeds next layer's agg) or f32 (last layer, for pooling).
#define NCOLT 4   // N/64 = 256/64
__global__ __launch_bounds__(256, 3) void gemm_bias_relu(const u16* __restrict__ Ah, const u16* __restrict__ Al,
                                                         const u16* __restrict__ Bh, const u16* __restrict__ Bl,
                                                         const float* __restrict__ bias,
                                                         const float* __restrict__ rowscale,
                                                         float* __restrict__ C, u16* __restrict__ Ch,
                                                         int M, int K, int N) {
    __shared__ __align__(16) u16 As_h[128 * 64];
    __shared__ __align__(16) u16 As_l[128 * 64];
    __shared__ __align__(16) u16 Bs_h[64 * 64];
    __shared__ __align__(16) u16 Bs_l[64 * 64];
    const int bid = blockIdx.x;
    const int slot = bid & 7;
    const int j = bid >> 3;
    const int ncol = j & (NCOLT - 1);
    const int rowhi = j / NCOLT;
    const int row_tile = rowhi * 8 + slot;
    const int row0 = row_tile * 128;
    if (row0 >= M) return;
    const int n0 = ncol * 64;
    const int tid = threadIdx.x;
    const int wave = tid >> 6, lane = tid & 63;
    const int wm = wave >> 1, wn = wave & 1;
    const int lr = lane >> 3;   // row within 8-row staging group
    const int lc = lane & 7;    // 16B-chunk position within row
    f32x4 acc[4][2] = {};

    for (int k0 = 0; k0 < K; k0 += 64) {
        // stage A hi/lo: 128 rows x 64 k, XOR-swizzled chunks
        #pragma unroll
        for (int q = 0; q < 4; ++q) {
            int rl = (wave * 4 + q) * 8 + lr;
            int ra = row0 + rl; ra = ra < M ? ra : (M - 1);   // clamp tail (rows >= M unused)
            int cg = (lc ^ (rl & 7)) << 3;
            gl_lds16(Ah + (size_t)ra * K + k0 + cg, &As_h[(wave * 4 + q) * 512]);
            gl_lds16(Al + (size_t)ra * K + k0 + cg, &As_l[(wave * 4 + q) * 512]);
        }
        // stage B^T hi/lo: 64 n-rows x 64 k
        #pragma unroll
        for (int q = 0; q < 2; ++q) {
            int rl = (wave * 2 + q) * 8 + lr;
            int ng = n0 + rl;
            int cg = (lc ^ (rl & 7)) << 3;
            gl_lds16(Bh + (size_t)ng * K + k0 + cg, &Bs_h[(wave * 2 + q) * 512]);
            gl_lds16(Bl + (size_t)ng * K + k0 + cg, &Bs_l[(wave * 2 + q) * 512]);
        }
        __syncthreads();
        #pragma unroll
        for (int kk = 0; kk < 2; ++kk) {
            const int cidx = kk * 4 + (lane >> 4);
            bf16x8 bhf[2], blf[2];
            #pragma unroll
            for (int nt = 0; nt < 2; ++nt) {
                int nl = wn * 32 + nt * 16 + (lane & 15);
                int off = nl * 64 + ((cidx ^ (nl & 7)) << 3);
                bhf[nt] = *(const bf16x8*)&Bs_h[off];
                blf[nt] = *(const bf16x8*)&Bs_l[off];
            }
            #pragma unroll
            for (int mt = 0; mt < 4; ++mt) {
                int ml = wm * 64 + mt * 16 + (lane & 15);
                int off = ml * 64 + ((cidx ^ (ml & 7)) << 3);
                bf16x8 ah = *(const bf16x8*)&As_h[off];
                bf16x8 al = *(const bf16x8*)&As_l[off];
                #pragma unroll
                for (int nt = 0; nt < 2; ++nt) {
                    acc[mt][nt] = __builtin_amdgcn_mfma_f32_16x16x32_bf16(ah, bhf[nt], acc[mt][nt], 0, 0, 0);
                    acc[mt][nt] = __builtin_amdgcn_mfma_f32_16x16x32_bf16(ah, blf[nt], acc[mt][nt], 0, 0, 0);
                    acc[mt][nt] = __builtin_amdgcn_mfma_f32_16x16x32_bf16(al, bhf[nt], acc[mt][nt], 0, 0, 0);
                }
            }
        }
        __syncthreads();
    }
    // epilogue: bias + relu (+ dinv row scale); C/D layout col=lane&15, row=(lane>>4)*4+r
    #pragma unroll
    for (int mt = 0; mt < 4; ++mt) {
        int gr = row0 + wm * 64 + mt * 16 + ((lane >> 4) << 2);
        #pragma unroll
        for (int r = 0; r < 4; ++r) {
            if (gr + r >= M) continue;
            float sc = rowscale ? rowscale[gr + r] : 1.f;
            #pragma unroll
            for (int nt = 0; nt < 2; ++nt) {
                int gc = n0 + wn * 32 + nt * 16 + (lane & 15);
                float v = sc * fmaxf(acc[mt][nt][r] + bias[gc], 0.f);
                if (Ch) Ch[(size_t)(gr + r) * N + gc] = f2h(v);
                else    C[(size_t)(gr + r) * N + gc] = v;
            }
        }
    }
}

// ---------------- pooling ----------------
#define POOL_CHUNK 32
__global__ __launch_bounds__(256) void pool_kernel(const float* __restrict__ h,
                                                   const int* __restrict__ batch,
                                                   float* __restrict__ pool_sum) {
    int f = threadIdx.x;
    int start = blockIdx.x * POOL_CHUNK;
    int end = start + POOL_CHUNK; end = end < N_NODES ? end : N_NODES;
    if (start >= N_NODES) return;
    int gcur = batch[start];
    float acc = 0.f;
    for (int i = start; i < end; ++i) {
        int g = batch[i];
        if (g != gcur) { atomicAdd(&pool_sum[gcur * HID + f], acc); acc = 0.f; gcur = g; }
        acc += h[(size_t)i * HID + f];
    }
    atomicAdd(&pool_sum[gcur * HID + f], acc);
}

__device__ int lb_int(const int* __restrict__ a, int n, int v) {
    int lo = 0, hi = n;
    while (lo < hi) {
        int mid = (lo + hi) >> 1;
        if (a[mid] < v) lo = mid + 1; else hi = mid;
    }
    return lo;
}

__global__ void final_linear_kernel(const float* __restrict__ pool_sum,
                                    const int* __restrict__ batch,
                                    const float* __restrict__ Wlin,
                                    const float* __restrict__ blin,
                                    float* __restrict__ out) {
    int idx = blockIdx.x * blockDim.x + threadIdx.x;
    if (idx >= N_GRAPHS * OUT_F) return;
    int g = idx / OUT_F, o = idx % OUT_F;
    int lo = lb_int(batch, N_NODES, g);
    int hi = lb_int(batch, N_NODES, g + 1);
    float cinv = 1.f / fmaxf((float)(hi - lo), 1.f);
    float s = blin[o];
    for (int k = 0; k < HID; ++k) s += (pool_sum[g * HID + k] * cinv) * Wlin[k * OUT_F + o];
    out[idx] = s;
}

// ---------------- launch ----------------
static inline size_t align_up(size_t x, size_t a) { return (x + a - 1) & ~(a - 1); }

extern "C" void kernel_launch(void* const* d_in, const int* in_sizes, int n_in,
                              void* d_out, int out_size, void* d_ws, size_t ws_size,
                              hipStream_t stream) {
    const float* x     = (const float*)d_in[0];
    const int*   elist = (const int*)d_in[1];   // [2, E]
    const int*   batch = (const int*)d_in[2];
    const float* W1    = (const float*)d_in[3];
    const float* b1    = (const float*)d_in[4];
    const float* Wm    = (const float*)d_in[5];
    const float* bm    = (const float*)d_in[6];
    const float* Wlin  = (const float*)d_in[7];
    const float* blin  = (const float*)d_in[8];
    float* outp = (float*)d_out;

    const int* srcA = elist;
    const int* dstA = elist + N_EDGES;

    char* ws = (char*)d_ws;
    size_t off = 0;
    float* h      = (float*)(ws + off); off = align_up(off + sizeof(float) * N_NODES * HID, 1024);
    u16*   h_half = (u16*)(ws + off);   off = align_up(off + sizeof(u16) * N_NODES * HID, 1024);
    u16*   xs     = (u16*)(ws + off);   off = align_up(off + sizeof(u16) * N_NODES * F_IN, 1024);
    u16*   g_hi   = (u16*)(ws + off);   off = align_up(off + sizeof(u16) * N_NODES * HID, 1024);
    u16*   g_lo   = (u16*)(ws + off);   off = align_up(off + sizeof(u16) * N_NODES * HID, 1024);
    u16*   W1T_h  = (u16*)(ws + off);   off = align_up(off + sizeof(u16) * F_IN * HID, 1024);
    u16*   W1T_l  = (u16*)(ws + off);   off = align_up(off + sizeof(u16) * F_IN * HID, 1024);
    u16*   WmT_h  = (u16*)(ws + off);   off = align_up(off + sizeof(u16) * (N_LAYERS - 1) * HID * HID, 1024);
    u16*   WmT_l  = (u16*)(ws + off);   off = align_up(off + sizeof(u16) * (N_LAYERS - 1) * HID * HID, 1024);
    int*   cursor = (int*)(ws + off);   off = align_up(off + sizeof(int) * N_NODES, 1024);
    float* dinv   = (float*)(ws + off); off = align_up(off + sizeof(float) * N_NODES, 1024);
    u16*   ell_col = (u16*)(ws + off);  off = align_up(off + sizeof(u16) * N_NODES * ELLCAP, 1024);
    float* pool_sum = (float*)(ws + off); off = align_up(off + sizeof(float) * N_GRAPHS * HID, 1024);

    hipMemsetAsync(cursor, 0, sizeof(int) * N_NODES, stream);
    hipMemsetAsync(ell_col, 0, sizeof(u16) * N_NODES * ELLCAP, stream);  // pad slots -> node 0 (masked)
    hipMemsetAsync(pool_sum, 0, sizeof(float) * N_GRAPHS * HID, stream);

    fill_ell_kernel<<<(N_EDGES + 255) / 256, 256, 0, stream>>>(srcA, dstA, cursor, ell_col, N_EDGES);
    dinv_kernel<<<(N_NODES + 255) / 256, 256, 0, stream>>>(cursor, dinv, N_NODES);
    prescale_x_kernel<<<(N_NODES * F_IN + 255) / 256, 256, 0, stream>>>(x, cursor, xs, N_NODES * F_IN);

    transpose_split_tiled<<<dim3((F_IN / 32) * (HID / 32), 1), 256, 0, stream>>>(W1, W1T_h, W1T_l, F_IN, HID);
    transpose_split_tiled<<<dim3((HID / 32) * (HID / 32), N_LAYERS - 1), 256, 0, stream>>>(Wm, WmT_h, WmT_l, HID, HID);

    const int n_row_tiles = (N_NODES + 127) / 128;            // 157
    const int ggrid = ((n_row_tiles + 7) / 8) * 8 * NCOLT;    // 640 (holes guarded in-kernel)
    // layer 1: g = agg(xs) [K=128]; h' = fp16(dinv * relu(g @ W1 + b1))
    agg_fsplit_h<F_IN><<<(N_NODES / 32) * (F_IN / 64), 256, 0, stream>>>(xs, ell_col, cursor, dinv, g_hi, g_lo);
    gemm_bias_relu<<<ggrid, 256, 0, stream>>>(g_hi, g_lo, W1T_h, W1T_l, b1, dinv, h, h_half, N_NODES, F_IN, HID);
    // middle layers: g = agg(h'); h' = dinv * relu(g @ W + b)
    // (last layer: unscaled, f32 output for pooling)
    for (int l = 0; l < N_LAYERS - 1; ++l) {
        agg_fsplit_h<HID><<<(N_NODES / 32) * (HID / 64), 256, 0, stream>>>(h_half, ell_col, cursor, dinv, g_hi, g_lo);
        const bool last = (l == N_LAYERS - 2);
        gemm_bias_relu<<<ggrid, 256, 0, stream>>>(g_hi, g_lo, WmT_h + (size_t)l * HID * HID,
                                                  WmT_l + (size_t)l * HID * HID,
                                                  bm + (size_t)l * HID,
                                                  last ? nullptr : dinv,
                                                  h, last ? nullptr : h_half,
                                                  N_NODES, HID, HID);
    }
    pool_kernel<<<(N_NODES + POOL_CHUNK - 1) / POOL_CHUNK, 256, 0, stream>>>(h, batch, pool_sum);
    final_linear_kernel<<<2, 256, 0, stream>>>(pool_sum, batch, Wlin, blin, outp);
}

// Round 3
// 1099.702 us; speedup vs baseline: 1.3201x; 1.0806x over previous
//
#include <hip/hip_runtime.h>

typedef unsigned short u16;
typedef unsigned int u32;
typedef __attribute__((ext_vector_type(8))) _Float16 f16x8;  // 8 fp16 = 4 VGPRs
typedef __attribute__((ext_vector_type(4))) float f32x4;
typedef __attribute__((ext_vector_type(8))) u16 u16x8;

#define N_NODES 20000
#define N_EDGES 320000
#define F_IN 128
#define HID 256
#define OUT_F 32
#define N_LAYERS 30
#define N_GRAPHS 16
#define ELLCAP 64

// ---------------- fp16 helpers ----------------
__device__ __forceinline__ float h2f(u16 u) {
    _Float16 h;
    __builtin_memcpy(&h, &u, 2);
    return (float)h;
}
__device__ __forceinline__ u16 f2h(float f) {
    _Float16 h = (_Float16)f;
    u16 u;
    __builtin_memcpy(&u, &h, 2);
    return u;
}

__device__ __forceinline__ void gl_lds16(const u16* g, u16* l) {
    __builtin_amdgcn_global_load_lds((const u32*)g, (u32*)l, 16, 0, 0);
}

// ---------------- graph build ----------------
// fill_ell also produces the degree: cursor's final value == in-degree at dst.
// ell_col is pre-zeroed; unfilled slots stay 0 (node 0: valid, masked off in agg).
__global__ void fill_ell_kernel(const int* __restrict__ src, const int* __restrict__ dst,
                                int* __restrict__ cursor, u16* __restrict__ ell_col, int E) {
    int e = blockIdx.x * blockDim.x + threadIdx.x;
    if (e >= E) return;
    int s = src[e], d = dst[e];
    int slot = atomicAdd(&cursor[d], 1);
    if (slot < ELLCAP) ell_col[d * ELLCAP + slot] = (u16)s;
}

__global__ void dinv_kernel(const int* __restrict__ cnt, float* __restrict__ dinv, int n) {
    int i = blockIdx.x * blockDim.x + threadIdx.x;
    if (i < n) dinv[i] = rsqrtf((float)(cnt[i] + 1));  // +1 self loop
}

// x' = fp16(dinv ⊙ x): gather source for layer-1 agg is fp16 (halves L2 line-touches)
__global__ void prescale_x_kernel(const float* __restrict__ x, const int* __restrict__ cnt,
                                  u16* __restrict__ xs, int total) {
    int i = blockIdx.x * 256 + threadIdx.x;
    if (i < total) xs[i] = f2h(x[i] * rsqrtf((float)(cnt[i >> 7] + 1)));   // F_IN = 128
}

// ---------------- weight transpose to fp16 (LDS-tiled, coalesced writes) ----------------
// W [L][K][N] (f32) -> T [L][N][K] (fp16); 32x32 tiles.
// Single fp16 weight array: the measured output error (absmax 1.5e-7 with fp16-h,
// split-bf16 W) shows a ~5e-4/layer operand-rounding source is invisible at the
// output — the network is contractive. fp16 W adds one more same-order source.
__global__ __launch_bounds__(256) void transpose_f16_tiled(const float* __restrict__ W,
                                                           u16* __restrict__ T,
                                                           int K, int N) {
    __shared__ float tile[32][33];
    const int l = blockIdx.y;
    const int ntn = N >> 5;
    const int kt = blockIdx.x / ntn, ntile = blockIdx.x % ntn;
    const float* Wl = W + (size_t)l * K * N;
    u16* Tl = T + (size_t)l * K * N;
    const int r8 = threadIdx.x >> 5, c = threadIdx.x & 31;
    #pragma unroll
    for (int rr = 0; rr < 4; ++rr) {
        int r = rr * 8 + r8;
        tile[r][c] = Wl[(size_t)(kt * 32 + r) * N + ntile * 32 + c];
    }
    __syncthreads();
    #pragma unroll
    for (int rr = 0; rr < 4; ++rr) {
        int n = rr * 8 + r8;                 // transposed row (N dim)
        float v = tile[c][n];                // W[k=kt*32+c][n]
        Tl[(size_t)(ntile * 32 + n) * K + kt * 32 + c] = f2h(v);
    }
}

// ---------------- feature-split aggregation (fp16 gather source, fp16 output) ----------------
// g[d] = dinv[d] * (sum_{s in N(d)} hs[s] + hs[d]), hs pre-scaled by dinv, stored fp16.
// Block = 32 nodes x one 64-feature chunk (one full 128B line per edge per chunk ->
// half the line-touches of the f32 version; the L2 request-rate roofline scales
// with bytes/feature). 8 lanes/node, u16x8 (8 fp16) per lane, f32 accumulate.
// fc = blockIdx & (CHUNKS-1): round-robin block->XCD pins one 2.56MB slice per XCD L2.
// Full 8-batches only (zero-padded ELL, masked final adds); depth-2 software pipeline.
// Output: single fp16 g (GEMM A operand is fp16 now — halves g write traffic).
template <int F>
__global__ __launch_bounds__(256) void agg_fsplit_h(const u16* __restrict__ hs,
                                                    const u16* __restrict__ ell_col,
                                                    const int* __restrict__ cnt,
                                                    const float* __restrict__ dinv,
                                                    u16* __restrict__ gout) {
    constexpr int CHUNKS = F / 64;
    __shared__ u16 cols[32 * ELLCAP];
    const int blk = blockIdx.x;
    const int fc = blk & (CHUNKS - 1);
    const int grp = blk / CHUNKS;
    const int node0 = grp * 32;
    const int tid = threadIdx.x;
    *(u16x8*)&cols[tid * 8] = *(const u16x8*)&ell_col[(size_t)node0 * ELLCAP + tid * 8];
    const int g = tid >> 3, sub = tid & 7;
    const int node = node0 + g;
    const int f = fc * 64 + sub * 8;
    int c = cnt[node]; c = c < ELLCAP ? c : ELLCAP;
    const float dd = dinv[node];
    f32x4 acc0 = {}, acc1 = {};
    {   // self loop (pre-scaled)
        u16x8 sv = *(const u16x8*)(hs + (size_t)node * F + f);
        #pragma unroll
        for (int i = 0; i < 4; ++i) acc0[i] += h2f(sv[i]);
        #pragma unroll
        for (int i = 0; i < 4; ++i) acc1[i] += h2f(sv[i + 4]);
    }
    __syncthreads();
    const u16* cl = &cols[g * ELLCAP];
    const int nb = (c + 7) >> 3;   // number of 8-batches (last one masked)
    if (nb > 0) {
        u16x8 vbuf[8];
        u16x8 cc = *(const u16x8*)&cl[0];
        #pragma unroll
        for (int j = 0; j < 8; ++j) vbuf[j] = *(const u16x8*)(hs + (size_t)cc[j] * F + f);
        int base = 0;
        for (int b = 1; b < nb; ++b) {
            u16x8 cn = *(const u16x8*)&cl[b * 8];
            u16x8 vn[8];
            #pragma unroll
            for (int j = 0; j < 8; ++j) vn[j] = *(const u16x8*)(hs + (size_t)cn[j] * F + f);
            #pragma unroll
            for (int j = 0; j < 8; ++j) {
                #pragma unroll
                for (int i = 0; i < 4; ++i) acc0[i] += h2f(vbuf[j][i]);
                #pragma unroll
                for (int i = 0; i < 4; ++i) acc1[i] += h2f(vbuf[j][i + 4]);
            }
            base += 8;
            #pragma unroll
            for (int j = 0; j < 8; ++j) vbuf[j] = vn[j];
        }
        const u16x8 zz = {};
        #pragma unroll
        for (int j = 0; j < 8; ++j) {
            u16x8 v = (base + j < c) ? vbuf[j] : zz;   // masked final batch (fp16 0x0000 == 0.0)
            #pragma unroll
            for (int i = 0; i < 4; ++i) acc0[i] += h2f(v[i]);
            #pragma unroll
            for (int i = 0; i < 4; ++i) acc1[i] += h2f(v[i + 4]);
        }
    }
    u16x8 vh;
    #pragma unroll
    for (int i = 0; i < 4; ++i) vh[i] = f2h(acc0[i] * dd);
    #pragma unroll
    for (int i = 0; i < 4; ++i) vh[i + 4] = f2h(acc1[i] * dd);
    *(u16x8*)(gout + (size_t)node * F + f) = vh;
}

// ---------------- fp16 MFMA GEMM + bias + relu (+ optional row scale) ----------------
// C[M][N] = rowscale[m] * relu(A[M][K] @ B^T + bias), A,B fp16, B transposed [N][K].
// SINGLE MFMA pass (was 3-pass split-bf16): A is fp16-derived anyway (11-bit), and
// measured output error shows ~5e-4/layer operand rounding is invisible (contractive net).
// Tile: 128(M) x 64(N) x 64(K). LDS 24KB -> 4 blocks/CU.
// XCD-swizzled 1D grid: id = 8*(rowhi*NCOLT + ncol) + slot, row_tile = rowhi*8 + slot.
// All NCOLT n-tiles of a row share id%8 -> same XCD; fp16 A slice (1.28MB/XCD) is
// fully L2-resident.
// Output: fp16 (Ch != nullptr, feeds next layer's agg) or f32 (last layer, for pooling).
#define NCOLT 4   // N/64 = 256/64
__global__ __launch_bounds__(256, 4) void gemm_bias_relu(const u16* __restrict__ A,
                                                         const u16* __restrict__ B,
                                                         const float* __restrict__ bias,
                                                         const float* __restrict__ rowscale,
                                                         float* __restrict__ C, u16* __restrict__ Ch,
                                                         int M, int K, int N) {
    __shared__ __align__(16) u16 As[128 * 64];
    __shared__ __align__(16) u16 Bs[64 * 64];
    const int bid = blockIdx.x;
    const int slot = bid & 7;
    const int j = bid >> 3;
    const int ncol = j & (NCOLT - 1);
    const int rowhi = j / NCOLT;
    const int row_tile = rowhi * 8 + slot;
    const int row0 = row_tile * 128;
    if (row0 >= M) return;
    const int n0 = ncol * 64;
    const int tid = threadIdx.x;
    const int wave = tid >> 6, lane = tid & 63;
    const int wm = wave >> 1, wn = wave & 1;
    const int lr = lane >> 3;   // row within 8-row staging group
    const int lc = lane & 7;    // 16B-chunk position within row
    f32x4 acc[4][2] = {};

    for (int k0 = 0; k0 < K; k0 += 64) {
        // stage A: 128 rows x 64 k, XOR-swizzled chunks
        #pragma unroll
        for (int q = 0; q < 4; ++q) {
            int rl = (wave * 4 + q) * 8 + lr;
            int ra = row0 + rl; ra = ra < M ? ra : (M - 1);   // clamp tail (rows >= M unused)
            int cg = (lc ^ (rl & 7)) << 3;
            gl_lds16(A + (size_t)ra * K + k0 + cg, &As[(wave * 4 + q) * 512]);
        }
        // stage B^T: 64 n-rows x 64 k
        #pragma unroll
        for (int q = 0; q < 2; ++q) {
            int rl = (wave * 2 + q) * 8 + lr;
            int ng = n0 + rl;
            int cg = (lc ^ (rl & 7)) << 3;
            gl_lds16(B + (size_t)ng * K + k0 + cg, &Bs[(wave * 2 + q) * 512]);
        }
        __syncthreads();
        #pragma unroll
        for (int kk = 0; kk < 2; ++kk) {
            const int cidx = kk * 4 + (lane >> 4);
            f16x8 bf[2];
            #pragma unroll
            for (int nt = 0; nt < 2; ++nt) {
                int nl = wn * 32 + nt * 16 + (lane & 15);
                int off = nl * 64 + ((cidx ^ (nl & 7)) << 3);
                bf[nt] = *(const f16x8*)&Bs[off];
            }
            #pragma unroll
            for (int mt = 0; mt < 4; ++mt) {
                int ml = wm * 64 + mt * 16 + (lane & 15);
                int off = ml * 64 + ((cidx ^ (ml & 7)) << 3);
                f16x8 af = *(const f16x8*)&As[off];
                #pragma unroll
                for (int nt = 0; nt < 2; ++nt) {
                    acc[mt][nt] = __builtin_amdgcn_mfma_f32_16x16x32_f16(af, bf[nt], acc[mt][nt], 0, 0, 0);
                }
            }
        }
        __syncthreads();
    }
    // epilogue: bias + relu (+ dinv row scale); C/D layout col=lane&15, row=(lane>>4)*4+r
    #pragma unroll
    for (int mt = 0; mt < 4; ++mt) {
        int gr = row0 + wm * 64 + mt * 16 + ((lane >> 4) << 2);
        #pragma unroll
        for (int r = 0; r < 4; ++r) {
            if (gr + r >= M) continue;
            float sc = rowscale ? rowscale[gr + r] : 1.f;
            #pragma unroll
            for (int nt = 0; nt < 2; ++nt) {
                int gc = n0 + wn * 32 + nt * 16 + (lane & 15);
                float v = sc * fmaxf(acc[mt][nt][r] + bias[gc], 0.f);
                if (Ch) Ch[(size_t)(gr + r) * N + gc] = f2h(v);
                else    C[(size_t)(gr + r) * N + gc] = v;
            }
        }
    }
}

// ---------------- pooling ----------------
#define POOL_CHUNK 32
__global__ __launch_bounds__(256) void pool_kernel(const float* __restrict__ h,
                                                   const int* __restrict__ batch,
                                                   float* __restrict__ pool_sum) {
    int f = threadIdx.x;
    int start = blockIdx.x * POOL_CHUNK;
    int end = start + POOL_CHUNK; end = end < N_NODES ? end : N_NODES;
    if (start >= N_NODES) return;
    int gcur = batch[start];
    float acc = 0.f;
    for (int i = start; i < end; ++i) {
        int g = batch[i];
        if (g != gcur) { atomicAdd(&pool_sum[gcur * HID + f], acc); acc = 0.f; gcur = g; }
        acc += h[(size_t)i * HID + f];
    }
    atomicAdd(&pool_sum[gcur * HID + f], acc);
}

__device__ int lb_int(const int* __restrict__ a, int n, int v) {
    int lo = 0, hi = n;
    while (lo < hi) {
        int mid = (lo + hi) >> 1;
        if (a[mid] < v) lo = mid + 1; else hi = mid;
    }
    return lo;
}

__global__ void final_linear_kernel(const float* __restrict__ pool_sum,
                                    const int* __restrict__ batch,
                                    const float* __restrict__ Wlin,
                                    const float* __restrict__ blin,
                                    float* __restrict__ out) {
    int idx = blockIdx.x * blockDim.x + threadIdx.x;
    if (idx >= N_GRAPHS * OUT_F) return;
    int g = idx / OUT_F, o = idx % OUT_F;
    int lo = lb_int(batch, N_NODES, g);
    int hi = lb_int(batch, N_NODES, g + 1);
    float cinv = 1.f / fmaxf((float)(hi - lo), 1.f);
    float s = blin[o];
    for (int k = 0; k < HID; ++k) s += (pool_sum[g * HID + k] * cinv) * Wlin[k * OUT_F + o];
    out[idx] = s;
}

// ---------------- launch ----------------
static inline size_t align_up(size_t x, size_t a) { return (x + a - 1) & ~(a - 1); }

extern "C" void kernel_launch(void* const* d_in, const int* in_sizes, int n_in,
                              void* d_out, int out_size, void* d_ws, size_t ws_size,
                              hipStream_t stream) {
    const float* x     = (const float*)d_in[0];
    const int*   elist = (const int*)d_in[1];   // [2, E]
    const int*   batch = (const int*)d_in[2];
    const float* W1    = (const float*)d_in[3];
    const float* b1    = (const float*)d_in[4];
    const float* Wm    = (const float*)d_in[5];
    const float* bm    = (const float*)d_in[6];
    const float* Wlin  = (const float*)d_in[7];
    const float* blin  = (const float*)d_in[8];
    float* outp = (float*)d_out;

    const int* srcA = elist;
    const int* dstA = elist + N_EDGES;

    char* ws = (char*)d_ws;
    size_t off = 0;
    float* h      = (float*)(ws + off); off = align_up(off + sizeof(float) * N_NODES * HID, 1024);
    u16*   h_half = (u16*)(ws + off);   off = align_up(off + sizeof(u16) * N_NODES * HID, 1024);
    u16*   xs     = (u16*)(ws + off);   off = align_up(off + sizeof(u16) * N_NODES * F_IN, 1024);
    u16*   g_buf  = (u16*)(ws + off);   off = align_up(off + sizeof(u16) * N_NODES * HID, 1024);
    u16*   W1T    = (u16*)(ws + off);   off = align_up(off + sizeof(u16) * F_IN * HID, 1024);
    u16*   WmT    = (u16*)(ws + off);   off = align_up(off + sizeof(u16) * (N_LAYERS - 1) * HID * HID, 1024);
    int*   cursor = (int*)(ws + off);   off = align_up(off + sizeof(int) * N_NODES, 1024);
    float* dinv   = (float*)(ws + off); off = align_up(off + sizeof(float) * N_NODES, 1024);
    u16*   ell_col = (u16*)(ws + off);  off = align_up(off + sizeof(u16) * N_NODES * ELLCAP, 1024);
    float* pool_sum = (float*)(ws + off); off = align_up(off + sizeof(float) * N_GRAPHS * HID, 1024);

    hipMemsetAsync(cursor, 0, sizeof(int) * N_NODES, stream);
    hipMemsetAsync(ell_col, 0, sizeof(u16) * N_NODES * ELLCAP, stream);  // pad slots -> node 0 (masked)
    hipMemsetAsync(pool_sum, 0, sizeof(float) * N_GRAPHS * HID, stream);

    fill_ell_kernel<<<(N_EDGES + 255) / 256, 256, 0, stream>>>(srcA, dstA, cursor, ell_col, N_EDGES);
    dinv_kernel<<<(N_NODES + 255) / 256, 256, 0, stream>>>(cursor, dinv, N_NODES);
    prescale_x_kernel<<<(N_NODES * F_IN + 255) / 256, 256, 0, stream>>>(x, cursor, xs, N_NODES * F_IN);

    transpose_f16_tiled<<<dim3((F_IN / 32) * (HID / 32), 1), 256, 0, stream>>>(W1, W1T, F_IN, HID);
    transpose_f16_tiled<<<dim3((HID / 32) * (HID / 32), N_LAYERS - 1), 256, 0, stream>>>(Wm, WmT, HID, HID);

    const int n_row_tiles = (N_NODES + 127) / 128;            // 157
    const int ggrid = ((n_row_tiles + 7) / 8) * 8 * NCOLT;    // 640 (holes guarded in-kernel)
    // layer 1: g = agg(xs) [K=128]; h' = fp16(dinv * relu(g @ W1 + b1))
    agg_fsplit_h<F_IN><<<(N_NODES / 32) * (F_IN / 64), 256, 0, stream>>>(xs, ell_col, cursor, dinv, g_buf);
    gemm_bias_relu<<<ggrid, 256, 0, stream>>>(g_buf, W1T, b1, dinv, h, h_half, N_NODES, F_IN, HID);
    // middle layers: g = agg(h'); h' = dinv * relu(g @ W + b)
    // (last layer: unscaled, f32 output for pooling)
    for (int l = 0; l < N_LAYERS - 1; ++l) {
        agg_fsplit_h<HID><<<(N_NODES / 32) * (HID / 64), 256, 0, stream>>>(h_half, ell_col, cursor, dinv, g_buf);
        const bool last = (l == N_LAYERS - 2);
        gemm_bias_relu<<<ggrid, 256, 0, stream>>>(g_buf, WmT + (size_t)l * HID * HID,
                                                  bm + (size_t)l * HID,
                                                  last ? nullptr : dinv,
                                                  h, last ? nullptr : h_half,
                                                  N_NODES, HID, HID);
    }
    pool_kernel<<<(N_NODES + POOL_CHUNK - 1) / POOL_CHUNK, 256, 0, stream>>>(h, batch, pool_sum);
    final_linear_kernel<<<2, 256, 0, stream>>>(pool_sum, batch, Wlin, blin, outp);
}

// Round 6
// 930.928 us; speedup vs baseline: 1.5594x; 1.1813x over previous
//
#include <hip/hip_runtime.h>

typedef unsigned short u16;
typedef unsigned int u32;
typedef __attribute__((ext_vector_type(8))) _Float16 f16x8;  // 8 fp16 = 4 VGPRs
typedef __attribute__((ext_vector_type(4))) float f32x4;
typedef __attribute__((ext_vector_type(8))) u16 u16x8;

#define N_NODES 20000
#define N_EDGES 320000
#define F_IN 128
#define HID 256
#define OUT_F 32
#define N_LAYERS 30
#define N_GRAPHS 16
#define ELLCAP 64

// ---------------- fp16 helpers ----------------
__device__ __forceinline__ float h2f(u16 u) {
    _Float16 h;
    __builtin_memcpy(&h, &u, 2);
    return (float)h;
}
__device__ __forceinline__ u16 f2h(float f) {
    _Float16 h = (_Float16)f;
    u16 u;
    __builtin_memcpy(&u, &h, 2);
    return u;
}

__device__ __forceinline__ void gl_lds16(const u16* g, u16* l) {
    __builtin_amdgcn_global_load_lds((const u32*)g, (u32*)l, 16, 0, 0);
}

// ---------------- graph build ----------------
// fill_ell also produces the degree: cursor's final value == in-degree at dst.
// ell_col is pre-zeroed; unfilled slots stay 0 (node 0: valid, masked off in agg).
__global__ void fill_ell_kernel(const int* __restrict__ src, const int* __restrict__ dst,
                                int* __restrict__ cursor, u16* __restrict__ ell_col, int E) {
    int e = blockIdx.x * blockDim.x + threadIdx.x;
    if (e >= E) return;
    int s = src[e], d = dst[e];
    int slot = atomicAdd(&cursor[d], 1);
    if (slot < ELLCAP) ell_col[d * ELLCAP + slot] = (u16)s;
}

__global__ void dinv_kernel(const int* __restrict__ cnt, float* __restrict__ dinv, int n) {
    int i = blockIdx.x * blockDim.x + threadIdx.x;
    if (i < n) dinv[i] = rsqrtf((float)(cnt[i] + 1));  // +1 self loop
}

// x' = fp16(dinv ⊙ x): layer-1 gather source (fp16 = the measured numerics floor;
// fp8 failed at 9.3e-6 vs threshold 1.86e-7, R4)
__global__ void prescale_x_kernel(const float* __restrict__ x, const int* __restrict__ cnt,
                                  u16* __restrict__ xs, int total) {
    int i = blockIdx.x * 256 + threadIdx.x;
    if (i < total) xs[i] = f2h(x[i] * rsqrtf((float)(cnt[i >> 7] + 1)));   // F_IN = 128
}

// ---------------- weight transpose to fp16 (LDS-tiled, coalesced writes) ----------------
// W [L][K][N] (f32) -> T [L][N][K] (fp16); 32x32 tiles.
__global__ __launch_bounds__(256) void transpose_f16_tiled(const float* __restrict__ W,
                                                           u16* __restrict__ T,
                                                           int K, int N) {
    __shared__ float tile[32][33];
    const int l = blockIdx.y;
    const int ntn = N >> 5;
    const int kt = blockIdx.x / ntn, ntile = blockIdx.x % ntn;
    const float* Wl = W + (size_t)l * K * N;
    u16* Tl = T + (size_t)l * K * N;
    const int r8 = threadIdx.x >> 5, c = threadIdx.x & 31;
    #pragma unroll
    for (int rr = 0; rr < 4; ++rr) {
        int r = rr * 8 + r8;
        tile[r][c] = Wl[(size_t)(kt * 32 + r) * N + ntile * 32 + c];
    }
    __syncthreads();
    #pragma unroll
    for (int rr = 0; rr < 4; ++rr) {
        int n = rr * 8 + r8;                 // transposed row (N dim)
        float v = tile[c][n];                // W[k=kt*32+c][n]
        Tl[(size_t)(ntile * 32 + n) * K + kt * 32 + c] = f2h(v);
    }
}

// ---------------- fused layer: agg -> LDS -> MFMA GEMM + bias + relu ----------------
// One kernel per GCN layer (was 2 dispatches + g round-trip through HBM).
// Block = 32 nodes, 256 threads (4 waves). Grid = 625 (= N_NODES/32), no tail.
//
// Phase 1 (agg): g[nd] = dinv ⊙ (Σ_{s∈N(nd)} hs[s] + hs[nd]), hs fp16 prescaled by dinv.
//   8 lanes/node × 8 features/lane, K/64 feature passes; per-neighbor ONE u16x8 (16B)
//   load; full 8-batches only (zero-padded ELL, masked final adds), depth-2 pipeline —
//   identical structure+accumulate order as the R3 standalone agg (numerics preserved).
//   Result rounded to fp16 and ds_written to gs with the 8-chunk XOR swizzle the MFMA
//   A-reads expect (chunk c at row r lives at r*K + ((c^(r&7))<<3)).
// Phase 2 (GEMM): h' = rowscale * relu(gs @ B^T + bias); B = [HID][K] fp16 streamed in
//   64-k chunks via global_load_lds (wave-uniform dest base + pre-swizzled src, both-
//   sides rule); wave w owns n∈[w*64,w*64+64): acc[2 m][4 n] f32x4. 2-barrier k-loop;
//   the k0=0 stage is issued at the end of phase 1 so its latency hides under agg drain.
// LDS: cols 4KB + gs 32*K*2 + Bs 32KB = 52KB (K=256) -> 3 blocks/CU; mem-phase blocks
//   overlap MFMA-phase blocks on the same CU (was impossible across dispatch barrier).
// Tradeoff (accepted, to be adjudicated by dur_us): per-XCD feature-slice L2 pinning is
//   lost — blocks gather full 512B rows from all of h (10.2MB); L2 misses fall to L3.
template <int K>
__global__ __launch_bounds__(256, 3) void layer_fused(const u16* __restrict__ hs,
                                                      const u16* __restrict__ B,
                                                      const u16* __restrict__ ell_col,
                                                      const int* __restrict__ cnt,
                                                      const float* __restrict__ dinv,
                                                      const float* __restrict__ bias,
                                                      const float* __restrict__ rowscale,
                                                      u16* __restrict__ Ch,
                                                      float* __restrict__ C) {
    __shared__ u16 cols[32 * ELLCAP];                 // 4 KB
    __shared__ __align__(16) u16 gs[32 * K];          // 16 KB (K=256) / 8 KB (K=128)
    __shared__ __align__(16) u16 Bs[256 * 64];        // 32 KB, n-major [256][64k]
    const int node0 = blockIdx.x * 32;
    const int tid = threadIdx.x;
    *(u16x8*)&cols[tid * 8] = *(const u16x8*)&ell_col[(size_t)node0 * ELLCAP + tid * 8];
    const int nd = tid >> 3, sub = tid & 7;
    const int node = node0 + nd;
    int c = cnt[node]; c = c < ELLCAP ? c : ELLCAP;
    const float dd = dinv[node];
    __syncthreads();                                   // cols staged
    const u16* cl = &cols[nd * ELLCAP];
    const int nb = (c + 7) >> 3;                       // 8-batches (last masked)

    // ---- phase 1: aggregate into gs ----
    #pragma unroll 1
    for (int p = 0; p < K / 64; ++p) {
        const int f = p * 64 + sub * 8;
        f32x4 a0 = {}, a1 = {};
        {   // self loop (pre-scaled)
            u16x8 sv = *(const u16x8*)(hs + (size_t)node * K + f);
            #pragma unroll
            for (int i = 0; i < 4; ++i) a0[i] += h2f(sv[i]);
            #pragma unroll
            for (int i = 0; i < 4; ++i) a1[i] += h2f(sv[i + 4]);
        }
        if (nb > 0) {
            u16x8 vbuf[8];
            u16x8 cc = *(const u16x8*)&cl[0];
            #pragma unroll
            for (int j = 0; j < 8; ++j) vbuf[j] = *(const u16x8*)(hs + (size_t)cc[j] * K + f);
            int base = 0;
            for (int b = 1; b < nb; ++b) {
                u16x8 cn = *(const u16x8*)&cl[b * 8];
                u16x8 vn[8];
                #pragma unroll
                for (int j = 0; j < 8; ++j) vn[j] = *(const u16x8*)(hs + (size_t)cn[j] * K + f);
                #pragma unroll
                for (int j = 0; j < 8; ++j) {
                    #pragma unroll
                    for (int i = 0; i < 4; ++i) a0[i] += h2f(vbuf[j][i]);
                    #pragma unroll
                    for (int i = 0; i < 4; ++i) a1[i] += h2f(vbuf[j][i + 4]);
                }
                base += 8;
                #pragma unroll
                for (int j = 0; j < 8; ++j) vbuf[j] = vn[j];
            }
            const u16x8 zz = {};
            #pragma unroll
            for (int j = 0; j < 8; ++j) {
                u16x8 v = (base + j < c) ? vbuf[j] : zz;   // masked final batch
                #pragma unroll
                for (int i = 0; i < 4; ++i) a0[i] += h2f(v[i]);
                #pragma unroll
                for (int i = 0; i < 4; ++i) a1[i] += h2f(v[i + 4]);
            }
        }
        u16x8 o;
        #pragma unroll
        for (int i = 0; i < 4; ++i) o[i] = f2h(a0[i] * dd);
        #pragma unroll
        for (int i = 0; i < 4; ++i) o[i + 4] = f2h(a1[i] * dd);
        const int cc_ = p * 8 + sub;                   // global 8-elem chunk index
        *(u16x8*)&gs[nd * K + ((cc_ ^ (nd & 7)) << 3)] = o;
    }

    // ---- phase 2: GEMM ----
    const int wave = tid >> 6, lane = tid & 63;
    const int lr = lane >> 3, lc = lane & 7;
    // early stage Bs(k0=0): latency hides under the agg drain + first barrier
    #pragma unroll
    for (int q = 0; q < 8; ++q) {
        int rl = (wave * 8 + q) * 8 + lr;              // B row (n), 0..255
        gl_lds16(B + (size_t)rl * K + ((lc ^ (rl & 7)) << 3), &Bs[(wave * 8 + q) * 512]);
    }
    f32x4 acc[2][4] = {};
    #pragma unroll
    for (int k = 0; k < K / 64; ++k) {
        __syncthreads();                               // gs + Bs(k) ready (drains vmcnt)
        const int k0 = k * 64;
        #pragma unroll
        for (int kk = 0; kk < 2; ++kk) {
            const int c8 = kk * 4 + (lane >> 4);       // chunk within 64-k tile, 0..7
            f16x8 bf[4];
            #pragma unroll
            for (int nt = 0; nt < 4; ++nt) {
                int n = wave * 64 + nt * 16 + (lane & 15);
                bf[nt] = *(const f16x8*)&Bs[n * 64 + ((c8 ^ (n & 7)) << 3)];
            }
            #pragma unroll
            for (int mt = 0; mt < 2; ++mt) {
                int ml = mt * 16 + (lane & 15);
                int cg = (k0 >> 3) + c8;               // global chunk index
                f16x8 af = *(const f16x8*)&gs[ml * K + ((cg ^ (ml & 7)) << 3)];
                #pragma unroll
                for (int nt = 0; nt < 4; ++nt)
                    acc[mt][nt] = __builtin_amdgcn_mfma_f32_16x16x32_f16(af, bf[nt], acc[mt][nt], 0, 0, 0);
            }
        }
        if (k + 1 < K / 64) {
            __syncthreads();                           // all waves done reading Bs(k)
            const int kn = k0 + 64;
            #pragma unroll
            for (int q = 0; q < 8; ++q) {
                int rl = (wave * 8 + q) * 8 + lr;
                gl_lds16(B + (size_t)rl * K + kn + ((lc ^ (rl & 7)) << 3), &Bs[(wave * 8 + q) * 512]);
            }
        }
    }
    // epilogue: bias + relu (+ dinv row scale); C/D layout col=lane&15, row=(lane>>4)*4+r
    #pragma unroll
    for (int mt = 0; mt < 2; ++mt) {
        int gr = node0 + mt * 16 + ((lane >> 4) << 2);
        #pragma unroll
        for (int r = 0; r < 4; ++r) {
            float sc = rowscale ? rowscale[gr + r] : 1.f;
            #pragma unroll
            for (int nt = 0; nt < 4; ++nt) {
                int gc = wave * 64 + nt * 16 + (lane & 15);
                float v = sc * fmaxf(acc[mt][nt][r] + bias[gc], 0.f);
                if (Ch) Ch[(size_t)(gr + r) * HID + gc] = f2h(v);
                else    C[(size_t)(gr + r) * HID + gc] = v;
            }
        }
    }
}

// ---------------- pooling ----------------
#define POOL_CHUNK 32
__global__ __launch_bounds__(256) void pool_kernel(const float* __restrict__ h,
                                                   const int* __restrict__ batch,
                                                   float* __restrict__ pool_sum) {
    int f = threadIdx.x;
    int start = blockIdx.x * POOL_CHUNK;
    int end = start + POOL_CHUNK; end = end < N_NODES ? end : N_NODES;
    if (start >= N_NODES) return;
    int gcur = batch[start];
    float acc = 0.f;
    for (int i = start; i < end; ++i) {
        int g = batch[i];
        if (g != gcur) { atomicAdd(&pool_sum[gcur * HID + f], acc); acc = 0.f; gcur = g; }
        acc += h[(size_t)i * HID + f];
    }
    atomicAdd(&pool_sum[gcur * HID + f], acc);
}

__device__ int lb_int(const int* __restrict__ a, int n, int v) {
    int lo = 0, hi = n;
    while (lo < hi) {
        int mid = (lo + hi) >> 1;
        if (a[mid] < v) lo = mid + 1; else hi = mid;
    }
    return lo;
}

__global__ void final_linear_kernel(const float* __restrict__ pool_sum,
                                    const int* __restrict__ batch,
                                    const float* __restrict__ Wlin,
                                    const float* __restrict__ blin,
                                    float* __restrict__ out) {
    int idx = blockIdx.x * blockDim.x + threadIdx.x;
    if (idx >= N_GRAPHS * OUT_F) return;
    int g = idx / OUT_F, o = idx % OUT_F;
    int lo = lb_int(batch, N_NODES, g);
    int hi = lb_int(batch, N_NODES, g + 1);
    float cinv = 1.f / fmaxf((float)(hi - lo), 1.f);
    float s = blin[o];
    for (int k = 0; k < HID; ++k) s += (pool_sum[g * HID + k] * cinv) * Wlin[k * OUT_F + o];
    out[idx] = s;
}

// ---------------- launch ----------------
static inline size_t align_up(size_t x, size_t a) { return (x + a - 1) & ~(a - 1); }

extern "C" void kernel_launch(void* const* d_in, const int* in_sizes, int n_in,
                              void* d_out, int out_size, void* d_ws, size_t ws_size,
                              hipStream_t stream) {
    const float* x     = (const float*)d_in[0];
    const int*   elist = (const int*)d_in[1];   // [2, E]
    const int*   batch = (const int*)d_in[2];
    const float* W1    = (const float*)d_in[3];
    const float* b1    = (const float*)d_in[4];
    const float* Wm    = (const float*)d_in[5];
    const float* bm    = (const float*)d_in[6];
    const float* Wlin  = (const float*)d_in[7];
    const float* blin  = (const float*)d_in[8];
    float* outp = (float*)d_out;

    const int* srcA = elist;
    const int* dstA = elist + N_EDGES;

    char* ws = (char*)d_ws;
    size_t off = 0;
    float* h      = (float*)(ws + off); off = align_up(off + sizeof(float) * N_NODES * HID, 1024);
    u16*   hA     = (u16*)(ws + off);   off = align_up(off + sizeof(u16) * N_NODES * HID, 1024);
    u16*   hB     = (u16*)(ws + off);   off = align_up(off + sizeof(u16) * N_NODES * HID, 1024);
    u16*   xs     = (u16*)(ws + off);   off = align_up(off + sizeof(u16) * N_NODES * F_IN, 1024);
    u16*   W1T    = (u16*)(ws + off);   off = align_up(off + sizeof(u16) * F_IN * HID, 1024);
    u16*   WmT    = (u16*)(ws + off);   off = align_up(off + sizeof(u16) * (N_LAYERS - 1) * HID * HID, 1024);
    int*   cursor = (int*)(ws + off);   off = align_up(off + sizeof(int) * N_NODES, 1024);
    float* dinv   = (float*)(ws + off); off = align_up(off + sizeof(float) * N_NODES, 1024);
    u16*   ell_col = (u16*)(ws + off);  off = align_up(off + sizeof(u16) * N_NODES * ELLCAP, 1024);
    float* pool_sum = (float*)(ws + off); off = align_up(off + sizeof(float) * N_GRAPHS * HID, 1024);

    hipMemsetAsync(cursor, 0, sizeof(int) * N_NODES, stream);
    hipMemsetAsync(ell_col, 0, sizeof(u16) * N_NODES * ELLCAP, stream);  // pad slots -> node 0 (masked)
    hipMemsetAsync(pool_sum, 0, sizeof(float) * N_GRAPHS * HID, stream);

    fill_ell_kernel<<<(N_EDGES + 255) / 256, 256, 0, stream>>>(srcA, dstA, cursor, ell_col, N_EDGES);
    dinv_kernel<<<(N_NODES + 255) / 256, 256, 0, stream>>>(cursor, dinv, N_NODES);
    prescale_x_kernel<<<(N_NODES * F_IN + 255) / 256, 256, 0, stream>>>(x, cursor, xs, N_NODES * F_IN);

    transpose_f16_tiled<<<dim3((F_IN / 32) * (HID / 32), 1), 256, 0, stream>>>(W1, W1T, F_IN, HID);
    transpose_f16_tiled<<<dim3((HID / 32) * (HID / 32), N_LAYERS - 1), 256, 0, stream>>>(Wm, WmT, HID, HID);

    const int lgrid = N_NODES / 32;   // 625, exact
    // layer 1: K = F_IN, gather from xs, write fp16 hA (double-buffer ping-pong after)
    layer_fused<F_IN><<<lgrid, 256, 0, stream>>>(xs, W1T, ell_col, cursor, dinv, b1, dinv, hA, h);
    u16* cur = hA; u16* nxt = hB;
    for (int l = 0; l < N_LAYERS - 1; ++l) {
        const bool last = (l == N_LAYERS - 2);
        layer_fused<HID><<<lgrid, 256, 0, stream>>>(cur, WmT + (size_t)l * HID * HID,
                                                    ell_col, cursor, dinv,
                                                    bm + (size_t)l * HID,
                                                    last ? nullptr : dinv,
                                                    last ? nullptr : nxt, h);
        u16* t = cur; cur = nxt; nxt = t;
    }
    pool_kernel<<<(N_NODES + POOL_CHUNK - 1) / POOL_CHUNK, 256, 0, stream>>>(h, batch, pool_sum);
    final_linear_kernel<<<2, 256, 0, stream>>>(pool_sum, batch, Wlin, blin, outp);
}